// Round 1
// baseline (326.774 us; speedup 1.0000x reference)
//
#include <hip/hip_runtime.h>

#define N_NODES 50000
#define N_EDGES 200000
#define IN1_SIZE 160
#define IN2_SIZE 4
#define W_SIZE 224
#define OUT_SIZE 480
#define INV_SQRT3 0.5773502691896258f
#define INV_SQRT2 0.7071067811865476f

// Zero the output buffer (capture-safe; harness poisons d_out with 0xAA).
__global__ void zero_out_kernel(float4* __restrict__ out, int n4) {
    const float4 z = make_float4(0.f, 0.f, 0.f, 0.f);
    for (int i = blockIdx.x * blockDim.x + threadIdx.x; i < n4;
         i += gridDim.x * blockDim.x) {
        out[i] = z;
    }
}

// One 64-lane wave per edge; each lane covers flat output indices
// lane, lane+64, ..., lane+448 (480 total, last iter half-masked).
__global__ __launch_bounds__(256) void tp_scatter_kernel(
    const float* __restrict__ in1,
    const float* __restrict__ in2,
    const float* __restrict__ weight,
    const int*   __restrict__ src,
    const int*   __restrict__ dst,
    float*       __restrict__ out)
{
    const int wave = threadIdx.x >> 6;
    const int lane = threadIdx.x & 63;
    const int e = blockIdx.x * 4 + wave;
    if (e >= N_EDGES) return;

    const int sn = src[e];
    const int dn = dst[e];

    const float* __restrict__ x = in1 + (long)sn * IN1_SIZE;
    const float* __restrict__ w = weight + (long)e * W_SIZE;

    const float y0  = in2[e * 4 + 0];
    const float y1x = in2[e * 4 + 1];
    const float y1y = in2[e * 4 + 2];
    const float y1z = in2[e * 4 + 3];

    float* __restrict__ o = out + (long)dn * OUT_SIZE;

    #pragma unroll
    for (int j = 0; j < 8; ++j) {
        const int idx = lane + (j << 6);
        if (idx >= OUT_SIZE) break;  // only j==7, lanes 32..63

        float val;
        if (idx < 64) {
            // p1[i] = w1[i] * s1[i] * y0
            val = w[idx] * x[idx] * y0;
        } else if (idx < 96) {
            // p4[u] = w4[u] * dot(v1[u], y1) * 1/sqrt(3)
            const int u = idx - 64;
            const float a0 = x[64 + 3 * u + 0];
            const float a1 = x[64 + 3 * u + 1];
            const float a2 = x[64 + 3 * u + 2];
            val = w[160 + u] * (a0 * y1x + a1 * y1y + a2 * y1z) * INV_SQRT3;
        } else if (idx < 288) {
            // p2[i][k] = w2[i] * s1[i] * y1[k]
            const int t = idx - 96;
            const int i = t / 3;
            const int k = t - 3 * i;
            const float yk = (k == 0) ? y1x : (k == 1) ? y1y : y1z;
            val = w[64 + i] * x[i] * yk;
        } else if (idx < 384) {
            // p3[u][k] = w3[u] * v1[u][k] * y0
            const int t = idx - 288;
            const int u = t / 3;
            const int k = t - 3 * u;
            val = w[128 + u] * x[64 + 3 * u + k] * y0;
        } else {
            // p5[u][k] = w5[u] * cross(v1[u], y1)[k] * 1/sqrt(2)
            const int t = idx - 384;
            const int u = t / 3;
            const int k = t - 3 * u;
            const float a0 = x[64 + 3 * u + 0];
            const float a1 = x[64 + 3 * u + 1];
            const float a2 = x[64 + 3 * u + 2];
            float c;
            if (k == 0)      c = a1 * y1z - a2 * y1y;
            else if (k == 1) c = a2 * y1x - a0 * y1z;
            else             c = a0 * y1y - a1 * y1x;
            val = w[192 + u] * c * INV_SQRT2;
        }
        atomicAdd(o + idx, val);
    }
}

extern "C" void kernel_launch(void* const* d_in, const int* in_sizes, int n_in,
                              void* d_out, int out_size, void* d_ws, size_t ws_size,
                              hipStream_t stream) {
    const float* in1    = (const float*)d_in[0];
    const float* in2    = (const float*)d_in[1];
    const float* weight = (const float*)d_in[2];
    const int*   src    = (const int*)d_in[3];
    const int*   dst    = (const int*)d_in[4];
    float* out = (float*)d_out;

    // Zero the output (atomic accumulation target).
    const int n4 = out_size / 4;  // 24,000,000 floats -> 6,000,000 float4
    zero_out_kernel<<<2048, 256, 0, stream>>>((float4*)out, n4);

    // One wave per edge, 4 waves (edges) per 256-thread block.
    const int blocks = (N_EDGES + 3) / 4;
    tp_scatter_kernel<<<blocks, 256, 0, stream>>>(in1, in2, weight, src, dst, out);
}